// Round 8
// baseline (461.311 us; speedup 1.0000x reference)
//
#include <hip/hip_runtime.h>

typedef _Float16 half8 __attribute__((ext_vector_type(8)));
typedef _Float16 half4t __attribute__((ext_vector_type(4)));
typedef _Float16 half2t __attribute__((ext_vector_type(2)));
typedef float float4t __attribute__((ext_vector_type(4)));
typedef float float4u __attribute__((ext_vector_type(4), aligned(4)));

#define BATCH 32
#define CIN 64
#define HIN 128
#define WIN 128
#define COUT 128
#define HOUT 126
#define WOUT 126
#define HP 63
#define WP 63
#define NGROUPS 16
#define CPG 8
#define EPSV 1e-5f

// xp row: 130 cols x 64 cins fp16 = 16640 B (8320 elems)
#define XPR 8320
#define XPRB 16640

// Fused prep kernel. grid (137, 32):
//   x < 128 : repack block (grow = x, b = y) — LDS-free transpose.
//   x >= 128: wt block (pos = x-128, grp = y); block (128,0) also zeroes stats.
__global__ __launch_bounds__(256) void prep_kernel(
    const float* __restrict__ x, const float* __restrict__ w,
    _Float16* __restrict__ xp, _Float16* __restrict__ wT,
    float* __restrict__ stats)
{
    const int tid = threadIdx.x;
    if (blockIdx.x >= 128) {
        // ---- weight transform: wT[pos][cout][cin] ----
        const int pos = blockIdx.x - 128;
        const int idx = blockIdx.y * 256 + tid;   // 0..8191 = cout*64+cin
        const int cout = idx >> 6, cin = idx & 63;
        wT[pos * (COUT * CIN) + idx] = (_Float16)w[(cout * CIN + cin) * 9 + pos];
        if (blockIdx.x == 128 && blockIdx.y == 0)
            ((float4t*)stats)[tid] = (float4t){0.f, 0.f, 0.f, 0.f};   // 1024 floats
        return;
    }

    const int grow = blockIdx.x;
    const int b = blockIdx.y;
    const int colq = tid >> 3;       // 0..31 -> cols 4*colq..4*colq+3
    const int chk  = tid & 7;        // cin chunk (8 cins)
    const int c0 = colq * 4;

    const float* xb = x + (((size_t)b * CIN + chk * 8) * HIN + grow) * WIN + c0;
    float4t v[8];
#pragma unroll
    for (int i = 0; i < 8; i++)
        v[i] = *(const float4t*)(xb + (size_t)i * HIN * WIN);

    _Float16* xpb = xp + ((size_t)b * HIN + grow) * XPR;
#pragma unroll
    for (int j = 0; j < 4; j++) {
        int col = c0 + j;
        int slot = chk ^ ((2 * grow + col) & 7);
        half8 h = { (_Float16)v[0][j], (_Float16)v[1][j], (_Float16)v[2][j],
                    (_Float16)v[3][j], (_Float16)v[4][j], (_Float16)v[5][j],
                    (_Float16)v[6][j], (_Float16)v[7][j] };
        *(half8*)(xpb + col * 64 + slot * 8) = h;   // 16B; 8 chk-lanes = 128B row
    }
    if (tid < 16) {                  // pad cols 128,129 = zeros
        int col = 128 + (tid >> 3), ck = tid & 7;
        int slot = ck ^ ((2 * grow + col) & 7);
        half8 z;
#pragma unroll
        for (int j = 0; j < 8; j++) z[j] = (_Float16)0.f;
        *(half8*)(xpb + col * 64 + slot * 8) = z;
    }
}

// Conv R8: wave = (row, nh); each wave computes ALL 128 couts for its 64 pixels
// of one output row. x fragments are DISJOINT per wave -> LDS read demand halved
// vs R7 (MFMA:ds_read = 8:1). All waves load the same weight frags per kk -> L1
// broadcast. 1-deep weight ring (a/na), full unroll, setprio around MFMA cluster.
// Epilogue: h-pool in-register, vertical combine via LDS scratch, fp16 {mx,mn}.
__global__ __launch_bounds__(256, 2) void conv_mfma_kernel(
    const _Float16* __restrict__ xp, const _Float16* __restrict__ wT,
    const float* __restrict__ bias, unsigned int* __restrict__ pl,
    float* __restrict__ stats)
{
    __shared__ __align__(16) _Float16 xs[4 * XPR];   // 66,560 B

    const int tid = threadIdx.x;
    // XCD-chunked remap (bijective: 2016 = 8*252)
    int f = blockIdx.y * 63 + blockIdx.x;
    int w = (f & 7) * 252 + (f >> 3);
    const int s = w % 63;
    const int b = w / 63;
    const int oy = 2 * s;

    const int lane = tid & 63;
    const int wv = tid >> 6;
    const int row = wv & 1;       // output row oy+row
    const int nh = wv >> 1;       // pixel half (64 px)
    const int m = lane & 15;
    const int q = lane >> 4;

    // ---- stage: rows oy..oy+3 contiguous in xp -> linear 66,560B copy ----
    {
        const char* src = (const char*)(xp + ((size_t)b * HIN + oy) * XPR);
#pragma unroll
        for (int k = 0; k < 16; k++) {
            int chunk = wv * 16 + k;   // 0..63
            __builtin_amdgcn_global_load_lds(
                (const __attribute__((address_space(1))) void*)(src + chunk * 1024 + lane * 16),
                (__attribute__((address_space(3))) void*)((char*)xs + chunk * 1024), 16, 0, 0);
        }
        if (wv == 0) {
            __builtin_amdgcn_global_load_lds(
                (const __attribute__((address_space(1))) void*)(src + 65536 + lane * 16),
                (__attribute__((address_space(3))) void*)((char*)xs + 65536), 16, 0, 0);
        }
    }

    const _Float16* wBase = wT + (size_t)m * CIN + q * 8;  // + pos*COUT*CIN + sub*16*CIN + ch*32

    half8 a[8], na[8];
#pragma unroll
    for (int sub = 0; sub < 8; sub++)
        a[sub] = *(const half8*)(wBase + (size_t)sub * 16 * CIN);   // kk=0: pos0 ch0

    float bv[8];
#pragma unroll
    for (int sub = 0; sub < 8; sub++) bv[sub] = bias[sub * 16 + m];

    float4t acc[8][4];
#pragma unroll
    for (int sub = 0; sub < 8; sub++)
#pragma unroll
        for (int n = 0; n < 4; n++)
            acc[sub][n] = (float4t){0.f, 0.f, 0.f, 0.f};

    __syncthreads();

#pragma unroll
    for (int kk = 0; kk < 18; kk++) {
        const int pos = kk >> 1, ch = kk & 1;
        const int kh = (pos > 2) + (pos > 5);
        const int kw = pos - kh * 3;
        int key = (2 * (oy + row + kh) + m + kw) & 7;     // this wave's row oy+row+kh
        const _Float16* bb = &xs[(row + kh) * XPR + (m + kw) * 64 + (((q + 4 * ch) ^ key) << 3)];

        // 1-deep ring: issue kk+1's weight loads (L1-hot, covered by MFMA cluster)
        const int nk = (kk < 17) ? kk + 1 : 0;
        const int npos = nk >> 1, nch = nk & 1;
#pragma unroll
        for (int sub = 0; sub < 8; sub++)
            na[sub] = *(const half8*)(wBase + (size_t)npos * COUT * CIN
                                      + (size_t)sub * 16 * CIN + nch * 32);

        __builtin_amdgcn_s_setprio(1);
#pragma unroll
        for (int n = 0; n < 4; n++) {
            half8 bf = *(const half8*)(bb + (nh * 4 + n) * 1024);
#pragma unroll
            for (int sub = 0; sub < 8; sub++)
                acc[sub][n] = __builtin_amdgcn_mfma_f32_16x16x32_f16(bf, a[sub], acc[sub][n], 0, 0, 0);
        }
        __builtin_amdgcn_s_setprio(0);
#pragma unroll
        for (int sub = 0; sub < 8; sub++) a[sub] = na[sub];
    }

    // ---- epilogue phase A: bias, stats (own row), horizontal pool in-register ----
    float sv[8], ssv[8];
    half4t hmm[8][4];
#pragma unroll
    for (int sub = 0; sub < 8; sub++) { sv[sub] = 0.f; ssv[sub] = 0.f; }
#pragma unroll
    for (int sub = 0; sub < 8; sub++) {
#pragma unroll
        for (int n = 0; n < 4; n++) {
            int pix0 = nh * 64 + n * 16 + q * 4;
            float p0 = acc[sub][n][0] + bv[sub];
            float p1 = acc[sub][n][1] + bv[sub];
            float p2 = acc[sub][n][2] + bv[sub];
            float p3 = acc[sub][n][3] + bv[sub];
            sv[sub]  += p0 + p1;
            ssv[sub] += p0 * p0 + p1 * p1;
            if (pix0 != 124) {      // only (nh=1,n=3,q=3): pixels 126/127 invalid
                sv[sub]  += p2 + p3;
                ssv[sub] += p2 * p2 + p3 * p3;
            }
            float mx0 = fmaxf(p0, p1), mn0 = fminf(p0, p1);
            float mx1 = fmaxf(p2, p3), mn1 = fminf(p2, p3);
            hmm[sub][n] = (half4t){ (_Float16)mx0, (_Float16)mn0,
                                    (_Float16)mx1, (_Float16)mn1 };
        }
    }

    // ---- vertical combine across row-waves via LDS scratch (xs reuse) ----
    __syncthreads();                  // all xs K-loop reads complete
    half4t* sc = (half4t*)xs;         // 32 KB used
    if (row == 1) {
#pragma unroll
        for (int sub = 0; sub < 8; sub++)
#pragma unroll
            for (int n = 0; n < 4; n++)
                sc[((nh * 8 + sub) * 4 + n) * 64 + lane] = hmm[sub][n];
    }
    __syncthreads();
    if (row == 0) {
#pragma unroll
        for (int sub = 0; sub < 8; sub++) {
            const int c = sub * 16 + m;
#pragma unroll
            for (int n = 0; n < 4; n++) {
                half4t o2 = sc[((nh * 8 + sub) * 4 + n) * 64 + lane];
                half4t h = hmm[sub][n];
                half4t o = { h[0] > o2[0] ? h[0] : o2[0],
                             h[1] < o2[1] ? h[1] : o2[1],
                             h[2] > o2[2] ? h[2] : o2[2],
                             h[3] < o2[3] ? h[3] : o2[3] };
                unsigned int* dst = pl + (((size_t)b * COUT + c) * HP + s) * 64
                                    + nh * 32 + n * 8 + 2 * q;
                *(half4t*)dst = o;    // 8B; pooled col 63 garbage, never read
            }
        }
    }

    // ---- stats: reduce over lane bits {0,1,2,4,5}, atomics from lanes 0,8 ----
#pragma unroll
    for (int sub = 0; sub < 8; sub++) {
        float aa = sv[sub], cc = ssv[sub];
        aa += __shfl_xor(aa, 1);  cc += __shfl_xor(cc, 1);
        aa += __shfl_xor(aa, 2);  cc += __shfl_xor(cc, 2);
        aa += __shfl_xor(aa, 4);  cc += __shfl_xor(cc, 4);
        aa += __shfl_xor(aa, 16); cc += __shfl_xor(cc, 16);
        aa += __shfl_xor(aa, 32); cc += __shfl_xor(cc, 32);
        if ((lane & 55) == 0) {   // lanes 0 and 8
            int g = sub * 2 + ((lane >> 3) & 1);
            atomicAdd(&stats[(b * NGROUPS + g) * 2 + 0], aa);
            atomicAdd(&stats[(b * NGROUPS + g) * 2 + 1], cc);
        }
    }
}

// pl entry = half2 {mx, mn} per pooled col. out = max(A*mx+B, A*mn+B): exact for
// either sign of A.
__global__ __launch_bounds__(256) void norm_pool_kernel(
    const unsigned int* __restrict__ pl, const float* __restrict__ stats,
    const float* __restrict__ gnw, const float* __restrict__ gnb,
    const float* __restrict__ scale, float* __restrict__ out)
{
    const int t  = threadIdx.x & 15;        // pooled cols 4t..4t+3
    const int hs = threadIdx.x >> 4;
    const int hblk = blockIdx.x & 3;
    const int c = (blockIdx.x >> 2) & 127;
    const int b = blockIdx.x >> 9;
    const int hp = hblk * 16 + hs;

    const float N = (float)(CPG * HOUT * WOUT);
    int g = c >> 3;
    float sum   = stats[(b * NGROUPS + g) * 2 + 0];
    float sumsq = stats[(b * NGROUPS + g) * 2 + 1];
    float mean = sum / N;
    float var  = sumsq / N - mean * mean;
    float rstd = rsqrtf(var + EPSV);

    float gw = gnw[c] * rstd;
    float A  = gw * scale[c];
    float B2 = (gnb[c] - mean * gw) * scale[c];

    if (hp >= HP) return;

    const unsigned int* yp = pl + (((size_t)b * COUT + c) * HP + hp) * 64 + t * 4;
    half8 rv = *(const half8*)yp;   // 4 entries = {mx,mn}x4

    float o[4];
#pragma unroll
    for (int j = 0; j < 4; j++) {
        float vx = fmaf((float)rv[2 * j],     A, B2);
        float vn = fmaf((float)rv[2 * j + 1], A, B2);
        float mx = fmaxf(vx, vn);
        o[j] = fminf(fmaxf(mx, 0.0f), 1.0f);
    }

    float* op = out + (((size_t)b * COUT + c) * HP + hp) * WP + t * 4;
    if (t < 15) {
        *(float4u*)op = (float4u){o[0], o[1], o[2], o[3]};
    } else {          // pooled cols 60,61,62 valid; 63 is pad
        op[0] = o[0]; op[1] = o[1]; op[2] = o[2];
    }
}

extern "C" void kernel_launch(void* const* d_in, const int* in_sizes, int n_in,
                              void* d_out, int out_size, void* d_ws, size_t ws_size,
                              hipStream_t stream) {
    const float* x      = (const float*)d_in[0];
    const float* conv_w = (const float*)d_in[1];
    const float* conv_b = (const float*)d_in[2];
    const float* gnw    = (const float*)d_in[3];
    const float* gnb    = (const float*)d_in[4];
    const float* scale  = (const float*)d_in[5];
    float* out = (float*)d_out;

    const size_t pl_bytes = (size_t)BATCH * COUT * HP * 64 * 4;   // 66.1 MB
    unsigned int* pl = (unsigned int*)d_ws;
    float* stats = (float*)((char*)d_ws + pl_bytes);              // 4 KB reserved
    _Float16* wT = (_Float16*)((char*)d_ws + pl_bytes + 4096);    // 147,456 B
    _Float16* xp = (_Float16*)((char*)d_ws + pl_bytes + 4096 + 147456); // 68.2 MB

    // prep: repack (x<128) + wt (x>=128) + stats zeroing, one launch
    dim3 pgrid(137, BATCH);
    prep_kernel<<<pgrid, 256, 0, stream>>>(x, conv_w, xp, wT, stats);

    dim3 grid(HP, BATCH);   // 63 x 32 = 2016 blocks
    conv_mfma_kernel<<<grid, 256, 0, stream>>>(xp, wT, conv_b, pl, stats);

    norm_pool_kernel<<<BATCH * COUT * 4, 256, 0, stream>>>(
        pl, stats, gnw, gnb, scale, out);
}